// Round 12
// baseline (112.924 us; speedup 1.0000x reference)
//
#include <hip/hip_runtime.h>
#include <math.h>

#define CEPS 1e-9f

typedef _Float16 half8 __attribute__((ext_vector_type(8)));
typedef _Float16 h2 __attribute__((ext_vector_type(2)));
typedef __fp16 fp16x2 __attribute__((ext_vector_type(2)));
typedef float floatx16 __attribute__((ext_vector_type(16)));

// x  : [4,56,56,8,32] fp32    W: [4,4,128,32] fp32    bias: [128] fp32
// out: [4,112,112,128] fp32 act
//
// R24: pipelined ping-pong W-table (single kernel). History:
//  R19 (PASSED 102us bench, ~40us kernel): two-kernel reference.
//  R21 (FAILED): folded W-table; cross-rebuild LDS-load CSE (tiles {2,3}
//       got {0,1} weights). R23 confirmed by fixing it with laundering.
//  R22 (PASSED 110us): direct-global bf -> serialized L2 latency. bf must
//       come from LDS.
//  R23 (PASSED 109us, kernel 55us, VALU 29%): correct but slow -- exposed
//       rebuild window between halves + asm-VOLATILE laundering serialized
//       the K-loop's ds_reads (volatile asm is program-ordered).
//  R24: two 8KB table regions (A/B), four 1-n-tile K-passes (acc 32->16):
//       upfront build A(t0)+B(t1) under B1; pass t prefetches W(t+2) into
//       16 f32 regs (hides under MFMAs), converts at pass end, ds_writes at
//       NEXT pass start (post-barrier, into the region nobody reads). No
//       exposed load window. Laundering now NON-volatile asm with the pass
//       index as input: unique asm node per pass (kills R21's CSE) without
//       ordering constraints. Peak live ~86 < 102 cap. Votes bit-identical.
// LDS: [0,16000) xt | [16384,24576) regA | [24576,32768) regB |
//      after B4 whole 32KB = scx [w][pl*8+i][128] f16 votes.
// Barriers: B1, P01, P12, P23, B4.

template<int CTRL>
__device__ __forceinline__ float dpp_add(float v) {
    return v + __int_as_float(__builtin_amdgcn_update_dpp(
        0, __float_as_int(v), CTRL, 0xF, 0xF, false));
}
__device__ __forceinline__ h2 pkrtz(float a, float b) {
    return __builtin_bit_cast(h2, __builtin_amdgcn_cvt_pkrtz(a, b));
}
__device__ __forceinline__ float fdot2(h2 a, h2 b, float c) {
    return __builtin_amdgcn_fdot2(__builtin_bit_cast(fp16x2, a),
                                  __builtin_bit_cast(fp16x2, b), c, false);
}
__device__ __forceinline__ half8 cvt8(float4 a, float4 b) {
    half8 hv;
    hv[0] = (_Float16)a.x; hv[1] = (_Float16)a.y;
    hv[2] = (_Float16)a.z; hv[3] = (_Float16)a.w;
    hv[4] = (_Float16)b.x; hv[5] = (_Float16)b.y;
    hv[6] = (_Float16)b.z; hv[7] = (_Float16)b.w;
    return hv;
}

__global__ __launch_bounds__(256, 5) void caps_mfma(
    const float* __restrict__ x,
    const float* __restrict__ Wt,
    const float* __restrict__ bias,
    float* __restrict__ out)
{
    __shared__ __align__(16) unsigned char smem[32768];
    _Float16* xt   = (_Float16*)smem;                 // [0,16000)
    _Float16* regA = (_Float16*)(smem + 16384);       // 8 KB: tiles 0,2
    _Float16* regB = (_Float16*)(smem + 24576);       // 8 KB: tiles 1,3
    _Float16* scx  = (_Float16*)smem;                 // votes, after B4

    const int tid = threadIdx.x;
    const int tile = blockIdx.x;            // 0..195 : 14x14 tiles of 4x4 pixels
    const int tu = tile / 14, tv = tile - tu * 14;
    const int u0 = tu * 4, v0 = tv * 4;
    const int rh = blockIdx.y >> 1;         // p & 1
    const int rw = blockIdx.y & 1;          // q & 1
    const int bp = blockIdx.z;              // b'

    // ---- stage x: fp32 -> f16 tile [ri(5)][rj(5)][i(8)][ci padded 40] ----
    #pragma unroll
    for (int it = 0; it < 4; ++it) {
        int idx = tid + (it << 8);
        if (idx < 800) {
            int cell = idx >> 5;            // 0..24
            int r = idx & 31;
            int i = r >> 2;
            int ci0 = (r & 3) << 3;
            int ri = cell / 5, rj = cell - ri * 5;
            int gi = u0 + rh - 1 + ri;
            int gj = v0 + rw - 1 + rj;
            float tmp[8] = {0.f, 0.f, 0.f, 0.f, 0.f, 0.f, 0.f, 0.f};
            if ((unsigned)gi < 56u && (unsigned)gj < 56u) {
                const float* src = x + (((i & 3) * 56 + gi) * 56 + gj) * 256
                                     + ((bp * 2 + (i >> 2)) << 5) + ci0;
                float4 a0 = *(const float4*)src;
                float4 a1 = *(const float4*)(src + 4);
                tmp[0] = a0.x; tmp[1] = a0.y; tmp[2] = a0.z; tmp[3] = a0.w;
                tmp[4] = a1.x; tmp[5] = a1.y; tmp[6] = a1.z; tmp[7] = a1.w;
            }
            half8 hv;
            #pragma unroll
            for (int j = 0; j < 8; ++j) hv[j] = (_Float16)tmp[j];
            *(half8*)(xt + (cell * 8 + i) * 40 + ci0) = hv;
        }
    }

    // ---- upfront W-table build: tile 0 -> regA, tile 1 -> regB ----
    // slot en = s*64 + ll in [0,512), 8 f16 each; 2 entries/thread/region.
    #pragma unroll
    for (int rgi = 0; rgi < 2; ++rgi) {
        _Float16* dst = rgi ? regB : regA;
        #pragma unroll
        for (int k = 0; k < 2; ++k) {
            int en = tid + (k << 8);        // [0,512)
            int s  = en >> 6;
            int ll = en & 63;
            int n  = rgi * 32 + (ll & 31);
            int hh = ll >> 5;
            int ci0 = ((s & 1) << 4) + (hh << 3);
            int kh = ((s >> 2) << 1) + 1 - rh;
            int kw = (((s >> 1) & 1) << 1) + 1 - rw;
            const float* src = Wt + (((kh * 4 + kw) * 128 + n) << 5) + ci0;
            float4 w0 = *(const float4*)src;
            float4 w1 = *(const float4*)(src + 4);
            *(half8*)(dst + (en << 3)) = cvt8(w0, w1);
        }
    }
    __syncthreads();                        // B1: xt + regA(t0) + regB(t1)

    const int l = tid & 63;
    const int w = tid >> 6;                 // wave = u-row within tile
    const int col = l & 31, h = l >> 5;
    const int invA = (l & 31) * 40 + (h << 3);

    // routing lane mapping + bias hoist (latency hides under K-loop)
    const int e = l & 1;
    const int c = (l >> 1) & 7;
    const int pl = l >> 4;
    h2 bq[4];
    {
        const float* bpt = bias + (c << 4) + (e << 3);
        float4 b0 = *(const float4*)bpt;
        float4 b1 = *(const float4*)(bpt + 4);
        bq[0] = pkrtz(b0.x, b0.y); bq[1] = pkrtz(b0.z, b0.w);
        bq[2] = pkrtz(b1.x, b1.y); bq[3] = pkrtz(b1.z, b1.w);
    }

    // ---- 4 K-passes, one n-tile each; ping-pong table regions ----
    // pf[t][m] = (votes[j=2m], votes[j=2m+1]) at ca = 32t+col; j = pixl*4+il.
    h2 pf[4][8];
    float4 wpre[4];                         // prefetched W (next+1 tile), f32
    half8 wh[2];                            // converted, awaiting write
    #pragma unroll
    for (int tt = 0; tt < 4; ++tt) {
        _Float16* breg = (tt & 1) ? regB : regA;

        // write the tile prefetched in the PREVIOUS pass (post-barrier, into
        // the region the previous pass was reading -- now safe, and it will
        // be read only after the NEXT barrier).
        if (tt == 1 || tt == 2) {
            _Float16* dst = (tt == 1) ? regA : regB;
            #pragma unroll
            for (int k = 0; k < 2; ++k) {
                int en = tid + (k << 8);
                *(half8*)(dst + (en << 3)) = wh[k];
            }
        }
        // prefetch tile tt+2 into registers (L2 latency hides under MFMAs)
        if (tt < 2) {
            const int tn = tt + 2;
            #pragma unroll
            for (int k = 0; k < 2; ++k) {
                int en = tid + (k << 8);
                int s  = en >> 6;
                int ll = en & 63;
                int n  = tn * 32 + (ll & 31);
                int hh = ll >> 5;
                int ci0 = ((s & 1) << 4) + (hh << 3);
                int kh = ((s >> 2) << 1) + 1 - rh;
                int kw = (((s >> 1) & 1) << 1) + 1 - rw;
                const float* src = Wt + (((kh * 4 + kw) * 128 + n) << 5) + ci0;
                wpre[2 * k]     = *(const float4*)src;
                wpre[2 * k + 1] = *(const float4*)(src + 4);
            }
        }

        floatx16 acc;
        #pragma unroll
        for (int j = 0; j < 16; ++j) acc[j] = 0.f;
        #pragma unroll
        for (int s = 0; s < 8; ++s) {
            const int tkh = s >> 2;
            const int tkw = (s >> 1) & 1;
            const int row = w + 1 - tkh;
            int aoff = (row * 5 + 1 - tkw) * 320 + ((s & 1) << 4) + invA;
            // CSE/hoist fix (R14/R21/R23): non-volatile asm, pass index as
            // input -> unique node per pass (no cross-pass unification of
            // same-address reads against changed LDS contents), no ordering
            // constraint (R23's volatile serialized the loop).
            asm("" : "+v"(aoff) : "v"(tt));
            half8 af = *(const half8*)(xt + aoff);
            int boff = (((s << 6) + l) << 4);
            asm("" : "+v"(boff) : "v"(tt));
            half8 bf = *(const half8*)((const unsigned char*)breg + boff);
            acc = __builtin_amdgcn_mfma_f32_32x32x16_f16(af, bf, acc, 0, 0, 0);
        }
        #pragma unroll
        for (int m = 0; m < 8; ++m)
            pf[tt][m] = pkrtz(acc[2 * m], acc[2 * m + 1]);
        // convert the prefetched tile (loads have had a full pass to land)
        if (tt < 2) {
            wh[0] = cvt8(wpre[0], wpre[1]);
            wh[1] = cvt8(wpre[2], wpre[3]);
        }
        __builtin_amdgcn_sched_barrier(0);
        if (tt < 3) __syncthreads();        // P01 / P12 / P23
    }

    __syncthreads();                        // B4: xt + tables dead everywhere

    // ---- transpose ALL 4 pixels: votes -> scx[w][pl*8+i][128] ----
    // row = pixl*8 + i, i = 4h + il; addr(f16) = w*4096 + row*128 + ca.
    _Float16* wbW = scx + (w << 12);
    {
        _Float16* wp = wbW + (h << 9) + col;
        #pragma unroll
        for (int t = 0; t < 4; ++t)
            #pragma unroll
            for (int m = 0; m < 8; ++m) {
                h2 pp = pf[t][m];
                const int mpl = m >> 1;
                const int il0 = (2 * m) & 3;
                const int il1 = (2 * m + 1) & 3;
                wp[mpl * 1024 + il0 * 128 + t * 32] = pp[0];
                wp[mpl * 1024 + il1 * 128 + t * 32] = pp[1];
            }
    }
    // wave-local RAW through LDS: in-order DS per wave, no barrier needed.

    // ---- routing: lane = (pl, c, e); votes in registers ----
    h2 va[8][4];
    {
        const _Float16* rp = wbW + (pl << 10) + (c << 4) + (e << 3);
        #pragma unroll
        for (int i = 0; i < 8; ++i) {
            half8 vv = *(const half8*)(rp + (i << 7));
            va[i][0][0] = vv[0]; va[i][0][1] = vv[1];
            va[i][1][0] = vv[2]; va[i][1][1] = vv[3];
            va[i][2][0] = vv[4]; va[i][2][1] = vv[5];
            va[i][3][0] = vv[6]; va[i][3][1] = vv[7];
        }
    }

    const h2 c0125 = pkrtz(0.125f, 0.125f);
    h2 pre[4];
    float lgv[8];

    // ---- round 0: route = 1/8; i-sum = local pk_add tree ----
    #pragma unroll
    for (int d = 0; d < 4; ++d) {
        h2 s01 = va[0][d] + va[1][d];
        h2 s23 = va[2][d] + va[3][d];
        h2 s45 = va[4][d] + va[5][d];
        h2 s67 = va[6][d] + va[7][d];
        h2 s = (s01 + s23) + (s45 + s67);
        pre[d] = s * c0125 + bq[d];
    }
    {
        float n = fdot2(pre[0], pre[0], 0.f);
        n = fdot2(pre[1], pre[1], n);
        n = fdot2(pre[2], pre[2], n);
        n = fdot2(pre[3], pre[3], n);
        float nq = dpp_add<0xB1>(n);          // + e-partner -> 16-atom norm
        float sc = nq * __builtin_amdgcn_rcpf(1.f + nq)
                      * __builtin_amdgcn_rsqf(nq + CEPS);
        h2 sc2 = pkrtz(sc, sc);
        #pragma unroll
        for (int d = 0; d < 4; ++d) pre[d] *= sc2;      // pre = act
    }
    #pragma unroll
    for (int i = 0; i < 8; ++i) {
        float p = fdot2(va[i][0], pre[0], 0.f);
        p = fdot2(va[i][1], pre[1], p);
        p = fdot2(va[i][2], pre[2], p);
        p = fdot2(va[i][3], pre[3], p);
        lgv[i] = dpp_add<0xB1>(p);            // full 16-atom dot, per i
    }

    // ---- rounds 1,2 ----
    #pragma unroll
    for (int r = 1; r < 3; ++r) {
        // softmax over c (lane bits 1..3): xor2 / xor4 / xor8, all DPP.
        h2 rt2[8];
        #pragma unroll
        for (int i = 0; i < 8; ++i) {
            float ee = __expf(lgv[i]);
            float ss = dpp_add<0x4E>(ee);     // quad_perm xor2 : c^1
            ss = dpp_add<0x141>(ss);          // row_half_mirror == xor4 : c^2
            ss = dpp_add<0x128>(ss);          // row ror8 == xor8 : c^4
            float route = ee * __builtin_amdgcn_rcpf(ss);
            rt2[i] = pkrtz(route, route);
        }
        #pragma unroll
        for (int d = 0; d < 4; ++d) {
            h2 p0 = rt2[0] * va[0][d], p1 = rt2[1] * va[1][d];
            h2 p2 = rt2[2] * va[2][d], p3 = rt2[3] * va[3][d];
            h2 p4 = rt2[4] * va[4][d], p5 = rt2[5] * va[5][d];
            h2 p6 = rt2[6] * va[6][d], p7 = rt2[7] * va[7][d];
            h2 s = ((p0 + p1) + (p2 + p3)) + ((p4 + p5) + (p6 + p7));
            pre[d] = s + bq[d];
        }
        {
            float n = fdot2(pre[0], pre[0], 0.f);
            n = fdot2(pre[1], pre[1], n);
            n = fdot2(pre[2], pre[2], n);
            n = fdot2(pre[3], pre[3], n);
            float nq = dpp_add<0xB1>(n);
            float sc = nq * __builtin_amdgcn_rcpf(1.f + nq)
                          * __builtin_amdgcn_rsqf(nq + CEPS);
            h2 sc2 = pkrtz(sc, sc);
            #pragma unroll
            for (int d = 0; d < 4; ++d) pre[d] *= sc2;  // act
        }
        if (r < 2) {
            #pragma unroll
            for (int i = 0; i < 8; ++i) {
                float p = fdot2(va[i][0], pre[0], 0.f);
                p = fdot2(va[i][1], pre[1], p);
                p = fdot2(va[i][2], pre[2], p);
                p = fdot2(va[i][3], pre[3], p);
                lgv[i] += dpp_add<0xB1>(p);
            }
        }
    }

    // ---- store: every lane writes its 8 atoms = 2x float4, coalesced ----
    {
        const int p = ((u0 + w) << 1) + rh;
        const int q = ((v0 + pl) << 1) + rw;
        float* op = out + (((bp * 112 + p) * 112 + q) << 7) + (c << 4) + (e << 3);
        float4 o0 = make_float4((float)pre[0][0], (float)pre[0][1],
                                (float)pre[1][0], (float)pre[1][1]);
        float4 o1 = make_float4((float)pre[2][0], (float)pre[2][1],
                                (float)pre[3][0], (float)pre[3][1]);
        *(float4*)op = o0;
        *(float4*)(op + 4) = o1;
    }
}

extern "C" void kernel_launch(void* const* d_in, const int* in_sizes, int n_in,
                              void* d_out, int out_size, void* d_ws, size_t ws_size,
                              hipStream_t stream) {
    const float* x  = (const float*)d_in[0];
    const float* Wt = (const float*)d_in[1];
    const float* b  = (const float*)d_in[2];
    float* out = (float*)d_out;
    (void)d_ws; (void)ws_size;               // workspace unused

    dim3 grid(196, 4, 4);    // 14x14 4x4-pixel tiles, 4 parity classes, 4 b'
    caps_mfma<<<grid, 256, 0, stream>>>(x, Wt, b, out);
}

// Round 13
// 104.345 us; speedup vs baseline: 1.0822x; 1.0822x over previous
//
#include <hip/hip_runtime.h>
#include <math.h>

#define CEPS 1e-9f

typedef _Float16 half8 __attribute__((ext_vector_type(8)));
typedef _Float16 h2 __attribute__((ext_vector_type(2)));
typedef __fp16 fp16x2 __attribute__((ext_vector_type(2)));
typedef float floatx16 __attribute__((ext_vector_type(16)));

// x  : [4,56,56,8,32] fp32    W: [4,4,128,32] fp32    bias: [128] fp32
// out: [4,112,112,128] fp32 act
//
// R25 = R19 verbatim (REVERT, per R24 pre-commitment). Final structure.
// History of the fold experiments (R21-R24), all worse than this two-kernel
// form:
//  R21 (FAILED): folded double-buffered LDS W-table -> cross-rebuild
//       LDS-load CSE (identical addresses, changed contents) gave tiles
//       {2,3} tile-{0,1} weights. Diagnosed via R23.
//  R22 (110us): direct-global bf -> serialized L2 latency (VALU 19%).
//  R23 (109us, kernel 55us): laundered fold, correct but the rebuild window
//       + volatile-asm ordering cost ~15us of stalls.
//  R24 (113us, kernel 57us): ping-pong pipelined fold -- still ~15us worse;
//       extra barriers at 5 waves/SIMD + halved MFMA ILP (1 acc chain vs 2).
// Conclusion: prep_w's launch (~8us) is CHEAPER than any in-kernel build.
// This kernel: bench 102.2us, caps_mfma ~40us (below the harness's 43us
// poison fills), absmax 0.00390625. Bench anatomy: ~40us kernel + ~43us
// harness 262MB poison fill + launch/sync overhead -- the kernel side is at
// its issue-bound floor (VALU busy-time plateau R15-R18, then R19's
// instruction-count cut; occupancy pinned at 5 blocks/CU by 32KB LDS and
// the proven (256,5) spill-free register cap).

template<int CTRL>
__device__ __forceinline__ float dpp_add(float v) {
    return v + __int_as_float(__builtin_amdgcn_update_dpp(
        0, __float_as_int(v), CTRL, 0xF, 0xF, false));
}
__device__ __forceinline__ h2 pkrtz(float a, float b) {
    return __builtin_bit_cast(h2, __builtin_amdgcn_cvt_pkrtz(a, b));
}
__device__ __forceinline__ float fdot2(h2 a, h2 b, float c) {
    return __builtin_amdgcn_fdot2(__builtin_bit_cast(fp16x2, a),
                                  __builtin_bit_cast(fp16x2, b), c, false);
}

// B[k][n] fragment table: idx = ((parity*8 + s)*4 + t)*64 + l -> 8 f16
__global__ __launch_bounds__(256) void prep_w(const float* __restrict__ Wt,
                                              _Float16* __restrict__ wb) {
    int idx = blockIdx.x * 256 + threadIdx.x;    // [0, 8192)
    int parity = idx >> 11;
    int s = (idx >> 8) & 7;
    int t = (idx >> 6) & 3;
    int l = idx & 63;
    int rh = parity >> 1, rw = parity & 1;
    int n = t * 32 + (l & 31);
    int h = l >> 5;
    int ci0 = ((s & 1) << 4) + (h << 3);
    int kh = ((s >> 2) << 1) + 1 - rh;
    int kw = (((s >> 1) & 1) << 1) + 1 - rw;
    const float* src = Wt + (((kh * 4 + kw) * 128 + n) << 5) + ci0;
    float4 w0 = *(const float4*)src;
    float4 w1 = *(const float4*)(src + 4);
    half8 hv;
    hv[0] = (_Float16)w0.x; hv[1] = (_Float16)w0.y;
    hv[2] = (_Float16)w0.z; hv[3] = (_Float16)w0.w;
    hv[4] = (_Float16)w1.x; hv[5] = (_Float16)w1.y;
    hv[6] = (_Float16)w1.z; hv[7] = (_Float16)w1.w;
    *(half8*)(wb + ((long)idx << 3)) = hv;
}

__global__ __launch_bounds__(256, 5) void caps_mfma(
    const float* __restrict__ x,
    const _Float16* __restrict__ wb,
    const float* __restrict__ bias,
    float* __restrict__ out)
{
    // Shared buffer, two lifetimes:
    //  phase 1: xt = [cell(5x5)][i(8)][ci padded 32->40] f16, 16000 B
    //  phase 2: scxh = [wave(4)][pl(4)][i(8)][ca(128)] f16, 32768 B EXACTLY
    //           (163840/32768 = 5 blocks/CU, matching the (256,5) reg cap)
    __shared__ __align__(16) unsigned char smem[32768];
    _Float16* xt = (_Float16*)smem;
    _Float16* scxh = (_Float16*)smem;

    const int tid = threadIdx.x;
    const int tile = blockIdx.x;            // 0..195 : 14x14 tiles of 4x4 pixels
    const int tu = tile / 14, tv = tile - tu * 14;
    const int u0 = tu * 4, v0 = tv * 4;
    const int rh = blockIdx.y >> 1;         // p & 1
    const int rw = blockIdx.y & 1;          // q & 1
    const int bp = blockIdx.z;              // b'
    const _Float16* wsrc = wb + ((long)blockIdx.y << 14);   // parity slice, 16 KB

    // ---- stage x: fp32 -> f16 tile [ri(5)][rj(5)][i(8)][ci], zero-filled OOB ----
    #pragma unroll
    for (int it = 0; it < 4; ++it) {
        int idx = tid + (it << 8);
        if (idx < 800) {
            int cell = idx >> 5;            // 0..24
            int r = idx & 31;
            int i = r >> 2;
            int ci0 = (r & 3) << 3;
            int ri = cell / 5, rj = cell - ri * 5;
            int gi = u0 + rh - 1 + ri;
            int gj = v0 + rw - 1 + rj;
            float tmp[8] = {0.f, 0.f, 0.f, 0.f, 0.f, 0.f, 0.f, 0.f};
            if ((unsigned)gi < 56u && (unsigned)gj < 56u) {
                const float* src = x + (((i & 3) * 56 + gi) * 56 + gj) * 256
                                     + ((bp * 2 + (i >> 2)) << 5) + ci0;
                float4 a0 = *(const float4*)src;
                float4 a1 = *(const float4*)(src + 4);
                tmp[0] = a0.x; tmp[1] = a0.y; tmp[2] = a0.z; tmp[3] = a0.w;
                tmp[4] = a1.x; tmp[5] = a1.y; tmp[6] = a1.z; tmp[7] = a1.w;
            }
            half8 hv;
            #pragma unroll
            for (int j = 0; j < 8; ++j) hv[j] = (_Float16)tmp[j];
            *(half8*)(xt + (cell * 8 + i) * 40 + ci0) = hv;
        }
    }
    __syncthreads();

    const int l = tid & 63;
    const int w = tid >> 6;                 // wave = u-row within tile
    const int col = l & 31, h = l >> 5;
    const int invA = (l & 31) * 40 + (h << 3);

    // ---- MFMA K-loop, TWO passes of 2 n-tiles: acc is 32 AGPR (not 64). ----
    // pf[t][m] = (votes[j=2m], votes[j=2m+1]) at ca = 32t+col; j = pixl*4+il.
    h2 pf[4][8];
    #pragma unroll
    for (int half = 0; half < 2; ++half) {
        floatx16 acc0, acc1;
        #pragma unroll
        for (int j = 0; j < 16; ++j) { acc0[j] = 0.f; acc1[j] = 0.f; }
        const int tb = half << 1;
        #pragma unroll
        for (int s = 0; s < 8; ++s) {
            const int tkh = s >> 2;
            const int tkw = (s >> 1) & 1;
            const int row = w + 1 - tkh;
            int aoff = (row * 5 + 1 - tkw) * 320 + ((s & 1) << 4) + invA;
            // SPILL FIX (R14): opaque A-frag address prevents cross-half CSE
            // of the 8 identical xt loads (R13: +32 live VGPR -> spill).
            asm("" : "+v"(aoff));
            half8 af = *(const half8*)(xt + aoff);
            half8 bf0 = *(const half8*)(wsrc + (((s * 4 + tb) * 64 + l) << 3));
            half8 bf1 = *(const half8*)(wsrc + (((s * 4 + tb + 1) * 64 + l) << 3));
            acc0 = __builtin_amdgcn_mfma_f32_32x32x16_f16(af, bf0, acc0, 0, 0, 0);
            acc1 = __builtin_amdgcn_mfma_f32_32x32x16_f16(af, bf1, acc1, 0, 0, 0);
        }
        #pragma unroll
        for (int m = 0; m < 8; ++m) {
            pf[tb][m]     = pkrtz(acc0[2 * m], acc0[2 * m + 1]);
            pf[tb + 1][m] = pkrtz(acc1[2 * m], acc1[2 * m + 1]);
        }
        __builtin_amdgcn_sched_barrier(0);
    }

    // xt is dead; scxh aliases it. All waves must pass here before writing.
    __syncthreads();

    // ---- transpose ALL 4 pixels: votes -> scxh[w][pl][i][ca] ----
    // row = pixl*8 + i, i = 4h + il; addr(f16) = w*4096 + (pl*8+i)*128 + ca.
    _Float16* wbW = scxh + (w << 12);
    {
        _Float16* wp = wbW + (h << 9) + col;
        #pragma unroll
        for (int t = 0; t < 4; ++t)
            #pragma unroll
            for (int m = 0; m < 8; ++m) {
                h2 pp = pf[t][m];
                const int pixl = m >> 1;
                const int il0 = (2 * m) & 3;
                const int il1 = (2 * m + 1) & 3;
                wp[pixl * 1024 + il0 * 128 + t * 32] = pp[0];
                wp[pixl * 1024 + il1 * 128 + t * 32] = pp[1];
            }
    }
    // wave-local RAW through LDS: in-order DS per wave, no barrier needed.

    // ---- routing: lane = (pl = l>>4, c = (l>>1)&7, e = l&1) ----
    const int e = l & 1;
    const int c = (l >> 1) & 7;
    const int pl = l >> 4;

    // all 8 i-votes for my 8 atoms, in registers: 8x ds_read_b128
    h2 va[8][4];
    {
        const _Float16* rp = wbW + (pl << 10) + (c << 4) + (e << 3);
        #pragma unroll
        for (int i = 0; i < 8; ++i) {
            half8 vv = *(const half8*)(rp + (i << 7));
            va[i][0][0] = vv[0]; va[i][0][1] = vv[1];
            va[i][1][0] = vv[2]; va[i][1][1] = vv[3];
            va[i][2][0] = vv[4]; va[i][2][1] = vv[5];
            va[i][3][0] = vv[6]; va[i][3][1] = vv[7];
        }
    }

    // bias: my 8 atoms of capsule c
    h2 bq[4];
    {
        const float* bpt = bias + (c << 4) + (e << 3);
        float4 b0 = *(const float4*)bpt;
        float4 b1 = *(const float4*)(bpt + 4);
        bq[0] = pkrtz(b0.x, b0.y); bq[1] = pkrtz(b0.z, b0.w);
        bq[2] = pkrtz(b1.x, b1.y); bq[3] = pkrtz(b1.z, b1.w);
    }
    const h2 c0125 = pkrtz(0.125f, 0.125f);

    h2 pre[4];
    float lgv[8];

    // ---- round 0: route = 1/8; i-sum = local pk_add tree (butterfly order) ----
    #pragma unroll
    for (int d = 0; d < 4; ++d) {
        h2 s01 = va[0][d] + va[1][d];
        h2 s23 = va[2][d] + va[3][d];
        h2 s45 = va[4][d] + va[5][d];
        h2 s67 = va[6][d] + va[7][d];
        h2 s = (s01 + s23) + (s45 + s67);
        pre[d] = s * c0125 + bq[d];
    }
    {
        float n = fdot2(pre[0], pre[0], 0.f);
        n = fdot2(pre[1], pre[1], n);
        n = fdot2(pre[2], pre[2], n);
        n = fdot2(pre[3], pre[3], n);
        float nq = dpp_add<0xB1>(n);          // + e-partner -> full 16-atom norm
        float sc = nq * __builtin_amdgcn_rcpf(1.f + nq)
                      * __builtin_amdgcn_rsqf(nq + CEPS);
        h2 sc2 = pkrtz(sc, sc);
        #pragma unroll
        for (int d = 0; d < 4; ++d) pre[d] *= sc2;      // pre = act
    }
    #pragma unroll
    for (int i = 0; i < 8; ++i) {
        float p = fdot2(va[i][0], pre[0], 0.f);
        p = fdot2(va[i][1], pre[1], p);
        p = fdot2(va[i][2], pre[2], p);
        p = fdot2(va[i][3], pre[3], p);
        lgv[i] = dpp_add<0xB1>(p);            // full 16-atom dot, per i
    }

    // ---- rounds 1,2 ----
    #pragma unroll
    for (int r = 1; r < 3; ++r) {
        // softmax over c (lane bits 1..3): xor2 / xor4 / xor8, all DPP.
        // (bits 0..1 uniform before the mirror stage -> l^7 == l^4)
        h2 rt2[8];
        #pragma unroll
        for (int i = 0; i < 8; ++i) {
            float ee = __expf(lgv[i]);
            float ss = dpp_add<0x4E>(ee);     // quad_perm xor2 : c^1
            ss = dpp_add<0x141>(ss);          // row_half_mirror == xor4 : c^2
            ss = dpp_add<0x128>(ss);          // row ror8 == xor8 : c^4
            float route = ee * __builtin_amdgcn_rcpf(ss);
            rt2[i] = pkrtz(route, route);
        }
        #pragma unroll
        for (int d = 0; d < 4; ++d) {
            h2 p0 = rt2[0] * va[0][d], p1 = rt2[1] * va[1][d];
            h2 p2 = rt2[2] * va[2][d], p3 = rt2[3] * va[3][d];
            h2 p4 = rt2[4] * va[4][d], p5 = rt2[5] * va[5][d];
            h2 p6 = rt2[6] * va[6][d], p7 = rt2[7] * va[7][d];
            h2 s = ((p0 + p1) + (p2 + p3)) + ((p4 + p5) + (p6 + p7));
            pre[d] = s + bq[d];
        }
        {
            float n = fdot2(pre[0], pre[0], 0.f);
            n = fdot2(pre[1], pre[1], n);
            n = fdot2(pre[2], pre[2], n);
            n = fdot2(pre[3], pre[3], n);
            float nq = dpp_add<0xB1>(n);
            float sc = nq * __builtin_amdgcn_rcpf(1.f + nq)
                          * __builtin_amdgcn_rsqf(nq + CEPS);
            h2 sc2 = pkrtz(sc, sc);
            #pragma unroll
            for (int d = 0; d < 4; ++d) pre[d] *= sc2;  // act
        }
        if (r < 2) {
            #pragma unroll
            for (int i = 0; i < 8; ++i) {
                float p = fdot2(va[i][0], pre[0], 0.f);
                p = fdot2(va[i][1], pre[1], p);
                p = fdot2(va[i][2], pre[2], p);
                p = fdot2(va[i][3], pre[3], p);
                lgv[i] += dpp_add<0xB1>(p);
            }
        }
    }

    // ---- store: every lane writes its 8 atoms = 2x float4, coalesced ----
    {
        const int p = ((u0 + w) << 1) + rh;
        const int q = ((v0 + pl) << 1) + rw;
        float* op = out + (((bp * 112 + p) * 112 + q) << 7) + (c << 4) + (e << 3);
        float4 o0 = make_float4((float)pre[0][0], (float)pre[0][1],
                                (float)pre[1][0], (float)pre[1][1]);
        float4 o1 = make_float4((float)pre[2][0], (float)pre[2][1],
                                (float)pre[3][0], (float)pre[3][1]);
        *(float4*)op = o0;
        *(float4*)(op + 4) = o1;
    }
}

extern "C" void kernel_launch(void* const* d_in, const int* in_sizes, int n_in,
                              void* d_out, int out_size, void* d_ws, size_t ws_size,
                              hipStream_t stream) {
    const float* x  = (const float*)d_in[0];
    const float* Wt = (const float*)d_in[1];
    const float* b  = (const float*)d_in[2];
    float* out = (float*)d_out;
    _Float16* wb = (_Float16*)d_ws;          // 4 parities x 16384 f16 = 64 KB

    prep_w<<<32, 256, 0, stream>>>(Wt, wb);
    dim3 grid(196, 4, 4);    // 14x14 4x4-pixel tiles, 4 parity classes, 4 b'
    caps_mfma<<<grid, 256, 0, stream>>>(x, wb, b, out);
}